// Round 1
// baseline (89.887 us; speedup 1.0000x reference)
//
#include <hip/hip_runtime.h>

// YoloV3 decoder: predictions (1, 145152, 85) fp32 ->
//   out0: bboxes     (145152, 4)  xyxy, /1536
//   out1: scores     (145152,)    objectness * max(class)
//   out2: class_pred (145152,)    argmax(class) as float value
//   out3: detections (145152, 6)  {x,y,x2,y2, class_conf, class_pred}
// score_threshold input is unused by the reference.
//
// R1: drop the LDS staging entirely. The previous structure (1 wave/block,
// 21.76 KB LDS, full vmcnt(0) drain before compute) was latency-bound at
// ~1.75 waves/SIMD. Here each thread loads its own 85-float anchor row
// straight into VGPRs as 21x16B + 1 scalar load:
//   - anchor rows are 4B-aligned (340 B stride); gfx950 global loads
//     support unaligned multi-dword access, so dwordx4 at align-4 is fine.
//   - no LDS, no barrier, no full-drain: occupancy is VGPR-bound
//     (~16 waves/CU) and every wave keeps ~21 KB of loads in flight ->
//     deep MLP, should pin HBM BW instead of latency.

#define N_ANCH 145152
#define NCH 85
#define NCLS 80

constexpr float INV_IMG = 1.0f / 1536.0f;
constexpr int TPB = 256;

__global__ __launch_bounds__(TPB)
void yolo_decode(const float* __restrict__ pred, float* __restrict__ out) {
    const int a = blockIdx.x * TPB + threadIdx.x;   // grid covers exactly N_ANCH
    const float* __restrict__ p = pred + (size_t)a * NCH;

    // ---- Load the whole anchor row into registers (issue all loads first) ----
    float4 cls[20];                     // channels 5..84 (80 class scores)
    #pragma unroll
    for (int j = 0; j < 20; ++j)
        cls[j] = *(const float4*)(p + 5 + 4 * j);
    const float4 bb = *(const float4*)(p);          // channels 0..3
    const float obj = p[4];                         // channel 4

    // ---- argmax over 80 classes (strict > keeps first-max, matches jnp.argmax) ----
    float cmax = cls[0].x;
    int cidx = 0;
    #pragma unroll
    for (int j = 0; j < 20; ++j) {
        const float v0 = cls[j].x, v1 = cls[j].y, v2 = cls[j].z, v3 = cls[j].w;
        const int k = 4 * j;
        if (v0 > cmax) { cmax = v0; cidx = k;     }
        if (v1 > cmax) { cmax = v1; cidx = k + 1; }
        if (v2 > cmax) { cmax = v2; cidx = k + 2; }
        if (v3 > cmax) { cmax = v3; cidx = k + 3; }
    }

    // ---- bbox decode ----
    const float cx = bb.x * INV_IMG;
    const float cy = bb.y * INV_IMG;
    const float hw = bb.z * (INV_IMG * 0.5f);
    const float hh = bb.w * (INV_IMG * 0.5f);
    const float x0 = cx - hw, y0 = cy - hh;
    const float x1 = cx + hw, y1 = cy + hh;

    const float score = obj * cmax;
    const float clsf  = (float)cidx;

    // ---- stores (same layout as previous version) ----
    // out0: bboxes, float4 aligned coalesced store
    ((float4*)out)[a] = make_float4(x0, y0, x1, y1);
    // out1: scores
    out[4 * N_ANCH + a] = score;
    // out2: class_pred (as float value)
    out[5 * N_ANCH + a] = clsf;
    // out3: detections, 6 floats (24 B) per anchor, float2-aligned
    float2* det = (float2*)(out + 6 * (size_t)N_ANCH + (size_t)a * 6);
    det[0] = make_float2(x0, y0);
    det[1] = make_float2(x1, y1);
    det[2] = make_float2(cmax, clsf);
}

extern "C" void kernel_launch(void* const* d_in, const int* in_sizes, int n_in,
                              void* d_out, int out_size, void* d_ws, size_t ws_size,
                              hipStream_t stream) {
    const float* pred = (const float*)d_in[0];
    float* out = (float*)d_out;
    // 145152 / 256 = 567 blocks exactly, no tail
    yolo_decode<<<N_ANCH / TPB, TPB, 0, stream>>>(pred, out);
}

// Round 2
// 84.111 us; speedup vs baseline: 1.0687x; 1.0687x over previous
//
#include <hip/hip_runtime.h>
#include <float.h>

// YoloV3 decoder: predictions (1, 145152, 85) fp32 ->
//   out0: bboxes     (145152, 4)  xyxy, /1536
//   out1: scores     (145152,)    objectness * max(class)
//   out2: class_pred (145152,)    argmax(class) as float value
//   out3: detections (145152, 6)  {x,y,x2,y2, class_conf, class_pred}
//
// R2: 16-lane cooperative decode, register-only.
//   - R0 (LDS staging, 1 wave/block, vmcnt(0) drain) was latency-bound.
//   - R1 (per-thread 340B row loads) was request-rate-bound: 64 distinct
//     cache lines per load instruction.
//   Here lane li of a 16-lane group loads channels li+16k (k=0..5):
//   every load instruction covers 4 contiguous 64B clusters per wave
//   (near-ideal coalescing), ~30 VGPR / no LDS -> 32 waves/CU, each wave
//   holding 6 independent loads in flight -> ~49KB in flight per CU,
//   well past the ~12KB needed to pin HBM BW. Argmax done with a 4-step
//   shfl_xor butterfly (value desc, index asc tie-break = first-max,
//   matching jnp.argmax).

#define N_ANCH 145152
#define NCH 85

constexpr float INV_IMG = 1.0f / 1536.0f;
constexpr int TPB = 256;
constexpr int GRP = 16;              // lanes per anchor
constexpr int APB = TPB / GRP;       // 16 anchors per block

__global__ __launch_bounds__(TPB)
void yolo_decode(const float* __restrict__ pred, float* __restrict__ out) {
    const int t  = threadIdx.x;
    const int li = t & (GRP - 1);                 // lane within group
    const int a  = blockIdx.x * APB + (t >> 4);   // anchor index
    const float* __restrict__ p = pred + (size_t)a * NCH;

    // ---- 6 coalesced group-strided loads: channel = li + 16k ----
    const float r0 = p[li];
    const float r1 = p[li + 16];
    const float r2 = p[li + 32];
    const float r3 = p[li + 48];
    const float r4 = p[li + 64];
    const float r5 = (li < 5) ? p[li + 80] : -FLT_MAX;  // masked: avoids OOB on last row

    // ---- broadcast bbox/obj (channels 0..4 sit in lanes 0..4 of r0) ----
    const float bx  = __shfl(r0, 0, GRP);
    const float by  = __shfl(r0, 1, GRP);
    const float bw  = __shfl(r0, 2, GRP);
    const float bh  = __shfl(r0, 3, GRP);
    const float obj = __shfl(r0, 4, GRP);

    // ---- per-lane first-max scan over classes (class = channel - 5) ----
    // Per-lane class indices are ascending (li-5, li+11, li+27, li+43,
    // li+59, li+75), so strict > keeps the first (smallest-index) max.
    float v = (li >= 5) ? r0 : -FLT_MAX;   // k=0 is bbox/obj for li<5
    int   c = li - 5;
    if (r1 > v) { v = r1; c = li + 11; }
    if (r2 > v) { v = r2; c = li + 27; }
    if (r3 > v) { v = r3; c = li + 43; }
    if (r4 > v) { v = r4; c = li + 59; }
    if (r5 > v) { v = r5; c = li + 75; }   // r5 = -FLT_MAX for li>=5: never wins

    // ---- 16-lane butterfly reduce: max value, smallest index on ties ----
    #pragma unroll
    for (int m = 8; m >= 1; m >>= 1) {
        const float ov = __shfl_xor(v, m);
        const int   oc = __shfl_xor(c, m);
        if (ov > v || (ov == v && oc < c)) { v = ov; c = oc; }
    }
    // all 16 lanes now hold (cmax=v, cidx=c)

    // ---- bbox decode ----
    const float cx = bx * INV_IMG;
    const float cy = by * INV_IMG;
    const float hw = bw * (INV_IMG * 0.5f);
    const float hh = bh * (INV_IMG * 0.5f);
    const float x0 = cx - hw, y0 = cy - hh;
    const float x1 = cx + hw, y1 = cy + hh;
    const float score = obj * v;
    const float clsf  = (float)c;

    // ---- stores, spread across lanes of the group ----
    if (li == 0) {
        ((float4*)out)[a] = make_float4(x0, y0, x1, y1);          // out0
    } else if (li == 1) {
        out[4 * N_ANCH + a] = score;                              // out1
    } else if (li == 2) {
        out[5 * N_ANCH + a] = clsf;                               // out2
    } else if (li < 6) {
        float2* det = (float2*)(out + 6 * (size_t)N_ANCH + (size_t)a * 6);
        if      (li == 3) det[0] = make_float2(x0, y0);           // out3
        else if (li == 4) det[1] = make_float2(x1, y1);
        else              det[2] = make_float2(v, clsf);
    }
}

extern "C" void kernel_launch(void* const* d_in, const int* in_sizes, int n_in,
                              void* d_out, int out_size, void* d_ws, size_t ws_size,
                              hipStream_t stream) {
    const float* pred = (const float*)d_in[0];
    float* out = (float*)d_out;
    // 145152 / 16 anchors-per-block = 9072 blocks exactly
    yolo_decode<<<N_ANCH / APB, TPB, 0, stream>>>(pred, out);
}

// Round 3
// 83.381 us; speedup vs baseline: 1.0780x; 1.0088x over previous
//
#include <hip/hip_runtime.h>
#include <float.h>

// YoloV3 decoder: predictions (1, 145152, 85) fp32 ->
//   out0: bboxes     (145152, 4)  xyxy, /1536
//   out1: scores     (145152,)    objectness * max(class)
//   out2: class_pred (145152,)    argmax(class) as float value
//   out3: detections (145152, 6)  {x,y,x2,y2, class_conf, class_pred}
//
// R3: discriminating probe. Evidence so far: three structurally disjoint
// kernels (R0 LDS-staged, R1 per-thread, R2 16-lane coop) all land at
// 83-90 us while every top-5 profile dispatch is the harness's 256 MiB
// poison fill (~43 us @ 78% HBM peak). Model: dur_us ~= 73 us fixed
// harness cost + ~10 us decode (data floor = 56 MB ~= 9 us).
// This round keeps R2's exact-fetch coalesced loads (lane li of a
// 16-lane group reads channels li+16k) and strips everything else:
//   - 512-thread blocks: 4536 blocks instead of 9072.
//   - value-only max reduce (4x shfl_xor + fmaxf), then first-max index
//     via (v==vmax ? c : INT_MAX) min-reduce (4x shfl_xor + min).
//     Per-lane scan with strict > keeps the smallest class index per
//     lane; global min over winning lanes = jnp.argmax first-max.
// If dur_us stays 82-85: fixed-cost confirmed -> kernel is at its
// memory floor; declare roofline.

#define N_ANCH 145152
#define NCH 85

constexpr float INV_IMG = 1.0f / 1536.0f;
constexpr int TPB = 512;
constexpr int GRP = 16;              // lanes per anchor
constexpr int APB = TPB / GRP;       // 32 anchors per block

__global__ __launch_bounds__(TPB)
void yolo_decode(const float* __restrict__ pred, float* __restrict__ out) {
    const int t  = threadIdx.x;
    const int li = t & (GRP - 1);                 // lane within group
    const int a  = blockIdx.x * APB + (t >> 4);   // anchor index
    const float* __restrict__ p = pred + (size_t)a * NCH;

    // ---- 6 coalesced group-strided loads: channel = li + 16k (exact fetch) ----
    const float r0 = p[li];
    const float r1 = p[li + 16];
    const float r2 = p[li + 32];
    const float r3 = p[li + 48];
    const float r4 = p[li + 64];
    const float r5 = (li < 5) ? p[li + 80] : -FLT_MAX;  // masked: no OOB on last row

    // ---- broadcast bbox/obj (channels 0..4 live in lanes 0..4 of r0) ----
    const float bx  = __shfl(r0, 0, GRP);
    const float by  = __shfl(r0, 1, GRP);
    const float bw  = __shfl(r0, 2, GRP);
    const float bh  = __shfl(r0, 3, GRP);
    const float obj = __shfl(r0, 4, GRP);

    // ---- per-lane first-max scan (class = channel - 5; per-lane indices ascend) ----
    float v = (li >= 5) ? r0 : -FLT_MAX;
    int   c = li - 5;
    if (r1 > v) { v = r1; c = li + 11; }
    if (r2 > v) { v = r2; c = li + 27; }
    if (r3 > v) { v = r3; c = li + 43; }
    if (r4 > v) { v = r4; c = li + 59; }
    if (r5 > v) { v = r5; c = li + 75; }   // r5 masked to -FLT_MAX for li>=5

    // ---- group reduce: max value, then min class index among winners ----
    float vmax = v;
    #pragma unroll
    for (int m = 8; m >= 1; m >>= 1)
        vmax = fmaxf(vmax, __shfl_xor(vmax, m));
    int cand = (v == vmax) ? c : 0x7fffffff;
    #pragma unroll
    for (int m = 8; m >= 1; m >>= 1)
        cand = min(cand, __shfl_xor(cand, m));
    // all 16 lanes hold (vmax, cand) = (class_conf, class_pred)

    // ---- bbox decode ----
    const float cx = bx * INV_IMG;
    const float cy = by * INV_IMG;
    const float hw = bw * (INV_IMG * 0.5f);
    const float hh = bh * (INV_IMG * 0.5f);
    const float x0 = cx - hw, y0 = cy - hh;
    const float x1 = cx + hw, y1 = cy + hh;
    const float score = obj * vmax;
    const float clsf  = (float)cand;

    // ---- stores, spread across lanes of the group ----
    if (li == 0) {
        ((float4*)out)[a] = make_float4(x0, y0, x1, y1);          // out0
    } else if (li == 1) {
        out[4 * N_ANCH + a] = score;                              // out1
    } else if (li == 2) {
        out[5 * N_ANCH + a] = clsf;                               // out2
    } else if (li < 6) {
        float2* det = (float2*)(out + 6 * (size_t)N_ANCH + (size_t)a * 6);
        if      (li == 3) det[0] = make_float2(x0, y0);           // out3
        else if (li == 4) det[1] = make_float2(x1, y1);
        else              det[2] = make_float2(vmax, clsf);
    }
}

extern "C" void kernel_launch(void* const* d_in, const int* in_sizes, int n_in,
                              void* d_out, int out_size, void* d_ws, size_t ws_size,
                              hipStream_t stream) {
    const float* pred = (const float*)d_in[0];
    float* out = (float*)d_out;
    // 145152 / 32 anchors-per-block = 4536 blocks exactly
    yolo_decode<<<N_ANCH / APB, TPB, 0, stream>>>(pred, out);
}